// Round 1
// baseline (717.436 us; speedup 1.0000x reference)
//
#include <hip/hip_runtime.h>

// e3LayerNorm: irreps 128x0e + 64x1o + 32x2e, TOTAL=480 cols, B=64 graphs.
// Strategy: 3 kernels.
//  k_stats   : per-graph sum[480] + sumsq[128] + deg via chunked register
//              accumulation (batch sorted) + boundary-flush atomics.
//  k_final   : build scale[64][480], off[64][480]  (out = x*scale + off).
//  k_apply   : pure fused-multiply-add streaming pass, float4.

#define TOTAL   480
#define NVEC    120    // TOTAL/4
#define NSCAL   128    // scalar (0e) columns
#define NGRAPH  64
#define CHUNK   128
#define EPS     1e-5f

// workspace layout (floats)
#define WS_SUMS   0                       // [64*480]
#define WS_SQ     (NGRAPH*TOTAL)          // [64*128]
#define WS_DEG    (WS_SQ + NGRAPH*NSCAL)  // [64]
#define WS_SCALE  (WS_DEG + NGRAPH)       // [64*480]
#define WS_OFF    (WS_SCALE + NGRAPH*TOTAL) // [64*480]
#define WS_ZERO_FLOATS (WS_DEG + NGRAPH)  // region that must be zeroed

__global__ __launch_bounds__(128) void k_stats(
    const float4* __restrict__ x, const int* __restrict__ batch,
    float* __restrict__ sums, float* __restrict__ sq, float* __restrict__ deg,
    int N)
{
    const int t  = threadIdx.x;          // 0..127, t<120 active for data
    const int r0 = blockIdx.x * CHUNK;
    const int rend = min(N, r0 + CHUNK);

    float sx = 0.f, sy = 0.f, sz = 0.f, sw = 0.f;
    float qx = 0.f, qy = 0.f, qz = 0.f, qw = 0.f;
    int g = batch[r0];
    int cnt = 0;

    for (int r = r0; r < rend; ++r) {
        int b = batch[r];
        if (b != g) {
            // flush accumulators for graph g (uniform branch: b from same addr)
            if (t < NVEC) {
                float* sp = sums + g * TOTAL + 4 * t;
                atomicAdd(sp + 0, sx); atomicAdd(sp + 1, sy);
                atomicAdd(sp + 2, sz); atomicAdd(sp + 3, sw);
                if (t < 32) {
                    float* qp = sq + g * NSCAL + 4 * t;
                    atomicAdd(qp + 0, qx); atomicAdd(qp + 1, qy);
                    atomicAdd(qp + 2, qz); atomicAdd(qp + 3, qw);
                }
            }
            if (t == 0) atomicAdd(deg + g, (float)cnt);
            sx = sy = sz = sw = 0.f;
            qx = qy = qz = qw = 0.f;
            cnt = 0;
            g = b;
        }
        if (t < NVEC) {
            float4 v = x[(long long)r * NVEC + t];
            sx += v.x; sy += v.y; sz += v.z; sw += v.w;
            if (t < 32) {
                qx += v.x * v.x; qy += v.y * v.y;
                qz += v.z * v.z; qw += v.w * v.w;
            }
        }
        ++cnt;
    }
    if (cnt > 0) {
        if (t < NVEC) {
            float* sp = sums + g * TOTAL + 4 * t;
            atomicAdd(sp + 0, sx); atomicAdd(sp + 1, sy);
            atomicAdd(sp + 2, sz); atomicAdd(sp + 3, sw);
            if (t < 32) {
                float* qp = sq + g * NSCAL + 4 * t;
                atomicAdd(qp + 0, qx); atomicAdd(qp + 1, qy);
                atomicAdd(qp + 2, qz); atomicAdd(qp + 3, qw);
            }
        }
        if (t == 0) atomicAdd(deg + g, (float)cnt);
    }
}

__global__ __launch_bounds__(128) void k_final(
    const float* __restrict__ sums, const float* __restrict__ sq,
    const float* __restrict__ deg, const float* __restrict__ weight,
    const float* __restrict__ bias,
    float* __restrict__ scale, float* __restrict__ off)
{
    const int b = blockIdx.x;          // graph
    const int t = threadIdx.x;         // 0..127, t<120 active

    const float invdeg = 1.0f / (deg[b] + 1e-12f);

    float m0 = 0.f, m1 = 0.f, m2 = 0.f, m3 = 0.f;
    float varp = 0.f;
    if (t < NVEC) {
        const float* sp = sums + b * TOTAL + 4 * t;
        m0 = sp[0] * invdeg; m1 = sp[1] * invdeg;
        m2 = sp[2] * invdeg; m3 = sp[3] * invdeg;
        if (t < 32) {
            const float* qp = sq + b * NSCAL + 4 * t;
            varp  = (qp[0] * invdeg - m0 * m0);
            varp += (qp[1] * invdeg - m1 * m1);
            varp += (qp[2] * invdeg - m2 * m2);
            varp += (qp[3] * invdeg - m3 * m3);
        }
    }
    if (t >= 32) varp = 0.f;

    __shared__ float s_rstd;
    if (t < 64) { // wave 0 reduce over lanes 0..31 (others contribute 0)
        for (int o = 16; o > 0; o >>= 1)
            varp += __shfl_down(varp, o, 64);
        if (t == 0)
            s_rstd = 1.0f / (sqrtf(varp * (1.0f / NSCAL)) + EPS);
    }
    __syncthreads();
    const float rstd = s_rstd;

    if (t < NVEC) {
        float mm[4] = {m0, m1, m2, m3};
        #pragma unroll
        for (int k = 0; k < 4; ++k) {
            int c = 4 * t + k;
            int widx;
            float sc, of;
            if (c < NSCAL) {
                widx = c;
                sc = weight[widx] * rstd;
                of = -mm[k] * sc + bias[c];
            } else if (c < NSCAL + 192) {
                widx = 128 + (c - 128) / 3;
                sc = weight[widx];
                of = -mm[k] * sc;
            } else {
                widx = 192 + (c - 320) / 5;
                sc = weight[widx];
                of = -mm[k] * sc;
            }
            scale[b * TOTAL + c] = sc;
            off[b * TOTAL + c]   = of;
        }
    }
}

__global__ __launch_bounds__(256) void k_apply(
    const float4* __restrict__ x, const int* __restrict__ batch,
    const float4* __restrict__ scale4, const float4* __restrict__ off4,
    float4* __restrict__ out, int total_vec)
{
    int i = blockIdx.x * 256 + threadIdx.x;
    if (i >= total_vec) return;
    int row = i / NVEC;
    int c4  = i - row * NVEC;
    int b   = batch[row];
    float4 v  = x[i];
    float4 sc = scale4[b * NVEC + c4];
    float4 of = off4[b * NVEC + c4];
    float4 o;
    o.x = fmaf(v.x, sc.x, of.x);
    o.y = fmaf(v.y, sc.y, of.y);
    o.z = fmaf(v.z, sc.z, of.z);
    o.w = fmaf(v.w, sc.w, of.w);
    out[i] = o;
}

extern "C" void kernel_launch(void* const* d_in, const int* in_sizes, int n_in,
                              void* d_out, int out_size, void* d_ws, size_t ws_size,
                              hipStream_t stream) {
    const float* x      = (const float*)d_in[0];
    const float* weight = (const float*)d_in[1];
    const float* bias   = (const float*)d_in[2];
    const int*   batch  = (const int*)d_in[3];
    const int N = in_sizes[0] / TOTAL;

    float* ws    = (float*)d_ws;
    float* sums  = ws + WS_SUMS;
    float* sq    = ws + WS_SQ;
    float* deg   = ws + WS_DEG;
    float* scale = ws + WS_SCALE;
    float* off   = ws + WS_OFF;

    // zero the accumulator region (harness poisons ws with 0xAA)
    hipMemsetAsync(ws, 0, WS_ZERO_FLOATS * sizeof(float), stream);

    int nblocks_stats = (N + CHUNK - 1) / CHUNK;
    k_stats<<<nblocks_stats, 128, 0, stream>>>(
        (const float4*)x, batch, sums, sq, deg, N);

    k_final<<<NGRAPH, 128, 0, stream>>>(sums, sq, deg, weight, bias, scale, off);

    int total_vec = N * NVEC;
    int nblocks_apply = (total_vec + 255) / 256;
    k_apply<<<nblocks_apply, 256, 0, stream>>>(
        (const float4*)x, batch, (const float4*)scale, (const float4*)off,
        (float4*)d_out, total_vec);
}